// Round 2
// baseline (766.824 us; speedup 1.0000x reference)
//
#include <hip/hip_runtime.h>

#define DIM 1024
#define SEQ 2048
#define BATCH 4
#define NH 16
#define HD 64
#define MLP 4096
#define ROWS (BATCH*SEQ)

typedef __bf16 bf16x8 __attribute__((ext_vector_type(8)));
typedef float f32x4 __attribute__((ext_vector_type(4)));
typedef __attribute__((address_space(3))) void as3void;
typedef const __attribute__((address_space(1))) void as1void;

__device__ __forceinline__ unsigned short f2bf(float f) {
  unsigned u = __builtin_bit_cast(unsigned, f);
  u = (u + 0x7FFFu + ((u >> 16) & 1u)) >> 16;
  return (unsigned short)u;
}

__device__ __forceinline__ void gload_lds16(const void* gp, const void* lp) {
  __builtin_amdgcn_global_load_lds(
      (as1void*)(unsigned long long)(size_t)gp,
      (as3void*)(unsigned int)(size_t)lp,
      16, 0, 0);
}

// ---------------- weight transpose fp32[K][N] -> bf16[N][K] ----------------
__global__ __launch_bounds__(256) void transpose_w_kernel(
    const float* __restrict__ in, unsigned short* __restrict__ out, int K, int N)
{
  __shared__ float tile[64][65];
  const int k0 = blockIdx.y * 64, n0 = blockIdx.x * 64;
  const int tc = threadIdx.x & 63, tr = threadIdx.x >> 6;
#pragma unroll
  for (int i = 0; i < 64; i += 4)
    tile[tr + i][tc] = in[(size_t)(k0 + tr + i) * N + n0 + tc];
  __syncthreads();
#pragma unroll
  for (int i = 0; i < 64; i += 4)
    out[(size_t)(n0 + tr + i) * K + k0 + tc] = f2bf(tile[tc][tr + i]);
}

// ---------------- layernorm fp32 -> bf16 ----------------
__global__ __launch_bounds__(256) void ln_kernel(
    const float* __restrict__ x, const float* __restrict__ w, const float* __restrict__ b,
    unsigned short* __restrict__ out)
{
  const int row = blockIdx.x;
  const int t = threadIdx.x;
  const int lane = t & 63, wave = t >> 6;
  const float* xr = x + (size_t)row * DIM;
  float4 v = *(const float4*)&xr[t * 4];
  float s = v.x + v.y + v.z + v.w;
  float s2 = v.x * v.x + v.y * v.y + v.z * v.z + v.w * v.w;
#pragma unroll
  for (int o = 1; o < 64; o <<= 1) {
    s += __shfl_xor(s, o);
    s2 += __shfl_xor(s2, o);
  }
  __shared__ float red[8];
  if (lane == 0) { red[wave] = s; red[4 + wave] = s2; }
  __syncthreads();
  s = red[0] + red[1] + red[2] + red[3];
  s2 = red[4] + red[5] + red[6] + red[7];
  const float mu = s * (1.f / DIM);
  const float var = s2 * (1.f / DIM) - mu * mu;
  const float rstd = rsqrtf(var + 1e-5f);
  float4 wv = *(const float4*)&w[t * 4];
  float4 bv = *(const float4*)&b[t * 4];
  ushort4 o;
  o.x = f2bf((v.x - mu) * rstd * wv.x + bv.x);
  o.y = f2bf((v.y - mu) * rstd * wv.y + bv.y);
  o.z = f2bf((v.z - mu) * rstd * wv.z + bv.z);
  o.w = f2bf((v.w - mu) * rstd * wv.w + bv.w);
  *(ushort4*)&out[(size_t)row * DIM + t * 4] = o;
}

// ---------------- GEMM: C[M][N] = A[M][K](bf16) x Bt[N][K](bf16) + bias ----------------
// m97 structure: 128x128 tile, BK=32, 4 waves, global_load_lds width 16.
// MODE 0: QKV scatter (Q scaled 0.125)  1: +res -> fp32  2: GELU -> bf16  3: +res -> fp32
template <int MODE>
__global__ __launch_bounds__(256) void gemm_bt(
    const unsigned short* __restrict__ A,
    const unsigned short* __restrict__ Bt,
    const float* __restrict__ bias,
    const float* resf, float* outf, unsigned short* outb,
    unsigned short* Qo, unsigned short* Ko, unsigned short* Vto,
    int M, int N, int K)
{
  __shared__ __align__(16) unsigned short sA[128 * 32];
  __shared__ __align__(16) unsigned short sB[128 * 32];
  const int tid = threadIdx.x;
  const int wave = tid >> 6, lane = tid & 63;

  // bijective XCD swizzle (all grids have nwg % 8 == 0)
  const int nbx = gridDim.x;
  const int nwg = nbx * gridDim.y;
  const int bid = blockIdx.y * nbx + blockIdx.x;
  const int cpx = nwg >> 3;
  const int swz = (bid & 7) * cpx + (bid >> 3);
  const int n0 = (swz % nbx) * 128;
  const int m0 = (swz / nbx) * 128;

  const int srow = wave * 16 + (lane >> 2);
  const int scol = (lane & 3) * 8;
  const unsigned short* gA = A + (size_t)(m0 + srow) * K + scol;
  const unsigned short* gB = Bt + (size_t)(n0 + srow) * K + scol;
  unsigned short* lA0 = sA + wave * 512;
  unsigned short* lA1 = sA + 2048 + wave * 512;
  unsigned short* lB0 = sB + wave * 512;
  unsigned short* lB1 = sB + 2048 + wave * 512;
  const size_t rstep = (size_t)64 * K;

  const int wr = wave >> 1, wc = wave & 1;
  const int fl = lane & 15, fh = lane >> 4;
  f32x4 acc[4][4] = {};

  for (int k0 = 0; k0 < K; k0 += 32) {
    gload_lds16(gA + k0, lA0);
    gload_lds16(gA + rstep + k0, lA1);
    gload_lds16(gB + k0, lB0);
    gload_lds16(gB + rstep + k0, lB1);
    __syncthreads();
    bf16x8 af[4], bfr[4];
#pragma unroll
    for (int f = 0; f < 4; ++f)
      af[f] = *(const bf16x8*)&sA[(wr * 64 + f * 16 + fl) * 32 + fh * 8];
#pragma unroll
    for (int f = 0; f < 4; ++f)
      bfr[f] = *(const bf16x8*)&sB[(wc * 64 + f * 16 + fl) * 32 + fh * 8];
#pragma unroll
    for (int i = 0; i < 4; ++i)
#pragma unroll
      for (int j = 0; j < 4; ++j)
        acc[i][j] = __builtin_amdgcn_mfma_f32_16x16x32_bf16(af[i], bfr[j], acc[i][j], 0, 0, 0);
    __syncthreads();
  }

#pragma unroll
  for (int i = 0; i < 4; ++i) {
    const int rowb = m0 + wr * 64 + i * 16 + fh * 4;
#pragma unroll
    for (int j = 0; j < 4; ++j) {
      const int col = n0 + wc * 64 + j * 16 + fl;
      const float bv = bias[col];
#pragma unroll
      for (int r = 0; r < 4; ++r) {
        const int row = rowb + r;
        float v = acc[i][j][r] + bv;
        if constexpr (MODE == 0) {
          const int which = col >> 10;
          const int h = (col >> 6) & 15;
          const int d = col & 63;
          const int b = row >> 11, s = row & 2047;
          const size_t bh = (size_t)(b * 16 + h);
          if (which == 0)      Qo[(bh * SEQ + s) * HD + d] = f2bf(v * 0.125f);
          else if (which == 1) Ko[(bh * SEQ + s) * HD + d] = f2bf(v);
          else                 Vto[(bh * HD + d) * SEQ + s] = f2bf(v);
        } else if constexpr (MODE == 2) {
          const float g = 0.5f * v * (1.0f + erff(v * 0.70710678118f));
          outb[(size_t)row * N + col] = f2bf(g);
        } else {
          outf[(size_t)row * N + col] = resf[(size_t)row * N + col] + v;
        }
      }
    }
  }
}

// ---------------- causal flash attention ----------------
// grid (16 qtiles, 64 bh); 4 waves; each wave owns 32 q-rows; K/V tiles of 64.
__global__ __launch_bounds__(256) void attn_kernel(
    const unsigned short* __restrict__ Q,
    const unsigned short* __restrict__ Kt,
    const unsigned short* __restrict__ Vt,
    unsigned short* __restrict__ Ao)
{
  __shared__ __align__(16) unsigned short sP[4 * 2048]; // 4KB per wave
  const int qt = blockIdx.x;
  const int bh = blockIdx.y;
  const int wave = threadIdx.x >> 6, lane = threadIdx.x & 63;
  const int fl = lane & 15, fh = lane >> 4;
  const int q0 = qt * 128;
  const int qw = q0 + wave * 32;
  const unsigned short* Qb = Q + (size_t)bh * SEQ * HD;
  const unsigned short* Kb = Kt + (size_t)bh * SEQ * HD;
  const unsigned short* Vb = Vt + (size_t)bh * HD * SEQ;
  char* pbase = (char*)sP + wave * 4096;

  bf16x8 aq[2][2];
#pragma unroll
  for (int fr = 0; fr < 2; ++fr)
#pragma unroll
    for (int kk = 0; kk < 2; ++kk)
      aq[fr][kk] = *(const bf16x8*)&Qb[(size_t)(qw + fr * 16 + fl) * HD + kk * 32 + fh * 8];

  f32x4 accO[2][4] = {};
  float mr[2][4], lr[2][4];
#pragma unroll
  for (int a = 0; a < 2; ++a)
#pragma unroll
    for (int b = 0; b < 4; ++b) { mr[a][b] = -1e30f; lr[a][b] = 0.f; }

  const int nkt = (q0 >> 6) + 2;
  for (int kt = 0; kt < nkt; ++kt) {
    const int kbase = kt * 64;
    if (kbase > qw + 31) break; // fully masked for this wave (wave-uniform)

    f32x4 accS[2][4] = {};
#pragma unroll
    for (int kk = 0; kk < 2; ++kk) {
      bf16x8 bk[4];
#pragma unroll
      for (int fc = 0; fc < 4; ++fc)
        bk[fc] = *(const bf16x8*)&Kb[(size_t)(kbase + fc * 16 + fl) * HD + kk * 32 + fh * 8];
#pragma unroll
      for (int fr = 0; fr < 2; ++fr)
#pragma unroll
        for (int fc = 0; fc < 4; ++fc)
          accS[fr][fc] = __builtin_amdgcn_mfma_f32_16x16x32_bf16(aq[fr][kk], bk[fc], accS[fr][fc], 0, 0, 0);
    }

    if (kbase + 63 > qw) { // causal mask needed
#pragma unroll
      for (int fr = 0; fr < 2; ++fr)
#pragma unroll
        for (int fc = 0; fc < 4; ++fc)
#pragma unroll
          for (int r = 0; r < 4; ++r) {
            const int colk = kbase + fc * 16 + fl;
            const int rowq = qw + fr * 16 + fh * 4 + r;
            if (colk > rowq) accS[fr][fc][r] = -1e30f;
          }
    }

    // online softmax per row (rows of a lane: fr*16 + fh*4 + r; cols across fl)
#pragma unroll
    for (int fr = 0; fr < 2; ++fr)
#pragma unroll
      for (int r = 0; r < 4; ++r) {
        float mx = fmaxf(fmaxf(accS[fr][0][r], accS[fr][1][r]),
                         fmaxf(accS[fr][2][r], accS[fr][3][r]));
        mx = fmaxf(mx, __shfl_xor(mx, 1));
        mx = fmaxf(mx, __shfl_xor(mx, 2));
        mx = fmaxf(mx, __shfl_xor(mx, 4));
        mx = fmaxf(mx, __shfl_xor(mx, 8));
        const float mnew = fmaxf(mr[fr][r], mx);
        const float alpha = __expf(mr[fr][r] - mnew);
        mr[fr][r] = mnew;
        float rs = 0.f;
#pragma unroll
        for (int fc = 0; fc < 4; ++fc) {
          const float p = __expf(accS[fr][fc][r] - mnew);
          accS[fr][fc][r] = p;
          rs += p;
        }
        rs += __shfl_xor(rs, 1);
        rs += __shfl_xor(rs, 2);
        rs += __shfl_xor(rs, 4);
        rs += __shfl_xor(rs, 8);
        lr[fr][r] = lr[fr][r] * alpha + rs;
#pragma unroll
        for (int dc = 0; dc < 4; ++dc)
          accO[fr][dc][r] *= alpha;
      }

    // P -> LDS bf16, XOR-swizzled rows (byte ^= (row&7)<<4)
#pragma unroll
    for (int fr = 0; fr < 2; ++fr)
#pragma unroll
      for (int fc = 0; fc < 4; ++fc)
#pragma unroll
        for (int r = 0; r < 4; ++r) {
          const int prow = fr * 16 + fh * 4 + r;
          const int cb = (fc * 16 + fl) * 2;
          *(unsigned short*)(pbase + prow * 128 + (cb ^ ((prow & 7) << 4))) = f2bf(accS[fr][fc][r]);
        }

    // PV: A = P (from LDS), B = V (from Vt, contiguous along s)
#pragma unroll
    for (int kk = 0; kk < 2; ++kk) {
      bf16x8 ap[2];
#pragma unroll
      for (int fr = 0; fr < 2; ++fr) {
        const int prow = fr * 16 + fl;
        const int kb = (kk * 32 + fh * 8) * 2;
        ap[fr] = *(const bf16x8*)(pbase + prow * 128 + (kb ^ ((prow & 7) << 4)));
      }
#pragma unroll
      for (int dc = 0; dc < 4; ++dc) {
        const bf16x8 bv = *(const bf16x8*)&Vb[(size_t)(dc * 16 + fl) * SEQ + kbase + kk * 32 + fh * 8];
#pragma unroll
        for (int fr = 0; fr < 2; ++fr)
          accO[fr][dc] = __builtin_amdgcn_mfma_f32_16x16x32_bf16(ap[fr], bv, accO[fr][dc], 0, 0, 0);
      }
    }
  }

  const int b = bh >> 4, h = bh & 15;
#pragma unroll
  for (int fr = 0; fr < 2; ++fr)
#pragma unroll
    for (int dc = 0; dc < 4; ++dc)
#pragma unroll
      for (int r = 0; r < 4; ++r) {
        const int row = qw + fr * 16 + fh * 4 + r;
        const int col = h * HD + dc * 16 + fl;
        const float v = accO[fr][dc][r] / lr[fr][r];
        Ao[((size_t)b * SEQ + row) * DIM + col] = f2bf(v);
      }
}

// ---------------- launcher ----------------
extern "C" void kernel_launch(void* const* d_in, const int* in_sizes, int n_in,
                              void* d_out, int out_size, void* d_ws, size_t ws_size,
                              hipStream_t stream)
{
  const float* x      = (const float*)d_in[0];
  const float* ln1_w  = (const float*)d_in[1];
  const float* ln1_b  = (const float*)d_in[2];
  const float* qkv_w  = (const float*)d_in[3];
  const float* qkv_b  = (const float*)d_in[4];
  const float* proj_w = (const float*)d_in[5];
  const float* proj_b = (const float*)d_in[6];
  const float* ln2_w  = (const float*)d_in[7];
  const float* ln2_b  = (const float*)d_in[8];
  const float* fc1_w  = (const float*)d_in[9];
  const float* fc1_b  = (const float*)d_in[10];
  const float* fc2_w  = (const float*)d_in[11];
  const float* fc2_b  = (const float*)d_in[12];
  float* out = (float*)d_out;
  unsigned short* ws = (unsigned short*)d_ws;

  // ws layout (bf16 element offsets); total = 125,829,120 bytes
  unsigned short* wqkv = ws;                 // [3072][1024]
  unsigned short* wproj = ws + 3145728;      // [1024][1024]
  unsigned short* wfc1 = ws + 4194304;       // [4096][1024]
  unsigned short* wfc2 = ws + 8388608;       // [1024][4096]
  unsigned short* xn1  = ws + 12582912;      // [8192][1024]
  unsigned short* Qb   = ws + 20971520;      // [B,H,S,D]
  unsigned short* Kb   = ws + 29360128;      // [B,H,S,D]
  unsigned short* Vtb  = ws + 37748736;      // [B,H,D,S]
  unsigned short* aout = xn1;                // reuse (xn1 dead after QKV gemm)
  unsigned short* hn   = Qb;                 // reuse (Q dead after attention)
  unsigned short* hbuf = Kb;                 // [8192][4096] overlaps K/Vt (dead)

  transpose_w_kernel<<<dim3(48, 16), 256, 0, stream>>>(qkv_w, wqkv, 1024, 3072);
  transpose_w_kernel<<<dim3(16, 16), 256, 0, stream>>>(proj_w, wproj, 1024, 1024);
  transpose_w_kernel<<<dim3(64, 16), 256, 0, stream>>>(fc1_w, wfc1, 1024, 4096);
  transpose_w_kernel<<<dim3(16, 64), 256, 0, stream>>>(fc2_w, wfc2, 4096, 1024);

  ln_kernel<<<ROWS, 256, 0, stream>>>(x, ln1_w, ln1_b, xn1);

  gemm_bt<0><<<dim3(24, 64), 256, 0, stream>>>(xn1, wqkv, qkv_b,
      nullptr, nullptr, nullptr, Qb, Kb, Vtb, ROWS, 3072, 1024);

  attn_kernel<<<dim3(16, 64), 256, 0, stream>>>(Qb, Kb, Vtb, aout);

  gemm_bt<1><<<dim3(8, 64), 256, 0, stream>>>(aout, wproj, proj_b,
      x, out, nullptr, nullptr, nullptr, nullptr, ROWS, 1024, 1024);

  ln_kernel<<<ROWS, 256, 0, stream>>>(out, ln2_w, ln2_b, hn);

  gemm_bt<2><<<dim3(32, 64), 256, 0, stream>>>(hn, wfc1, fc1_b,
      nullptr, nullptr, hbuf, nullptr, nullptr, nullptr, ROWS, 4096, 1024);

  gemm_bt<3><<<dim3(8, 64), 256, 0, stream>>>(hbuf, wfc2, fc2_b,
      out, out, nullptr, nullptr, nullptr, nullptr, ROWS, 1024, 4096);
}

// Round 3
// 725.419 us; speedup vs baseline: 1.0571x; 1.0571x over previous
//
#include <hip/hip_runtime.h>

#define DIM 1024
#define SEQ 2048
#define BATCH 4
#define NH 16
#define HD 64
#define MLP 4096
#define ROWS (BATCH*SEQ)

typedef __bf16 bf16x8 __attribute__((ext_vector_type(8)));
typedef float f32x4 __attribute__((ext_vector_type(4)));
typedef __attribute__((address_space(3))) void as3void;
typedef const __attribute__((address_space(1))) void as1void;

__device__ __forceinline__ unsigned short f2bf(float f) {
  unsigned u = __builtin_bit_cast(unsigned, f);
  u = (u + 0x7FFFu + ((u >> 16) & 1u)) >> 16;
  return (unsigned short)u;
}

__device__ __forceinline__ void gload_lds16(const void* gp, const void* lp) {
  __builtin_amdgcn_global_load_lds(
      (as1void*)(unsigned long long)(size_t)gp,
      (as3void*)(unsigned int)(size_t)lp,
      16, 0, 0);
}

// ---------------- weight transpose fp32[K][N] -> bf16[N][K] ----------------
__global__ __launch_bounds__(256) void transpose_w_kernel(
    const float* __restrict__ in, unsigned short* __restrict__ out, int K, int N)
{
  __shared__ float tile[64][65];
  const int k0 = blockIdx.y * 64, n0 = blockIdx.x * 64;
  const int tc = threadIdx.x & 63, tr = threadIdx.x >> 6;
#pragma unroll
  for (int i = 0; i < 64; i += 4)
    tile[tr + i][tc] = in[(size_t)(k0 + tr + i) * N + n0 + tc];
  __syncthreads();
#pragma unroll
  for (int i = 0; i < 64; i += 4)
    out[(size_t)(n0 + tr + i) * K + k0 + tc] = f2bf(tile[tc][tr + i]);
}

// ---------------- layernorm fp32 -> bf16 ----------------
__global__ __launch_bounds__(256) void ln_kernel(
    const float* __restrict__ x, const float* __restrict__ w, const float* __restrict__ b,
    unsigned short* __restrict__ out)
{
  const int row = blockIdx.x;
  const int t = threadIdx.x;
  const int lane = t & 63, wave = t >> 6;
  const float* xr = x + (size_t)row * DIM;
  float4 v = *(const float4*)&xr[t * 4];
  float s = v.x + v.y + v.z + v.w;
  float s2 = v.x * v.x + v.y * v.y + v.z * v.z + v.w * v.w;
#pragma unroll
  for (int o = 1; o < 64; o <<= 1) {
    s += __shfl_xor(s, o);
    s2 += __shfl_xor(s2, o);
  }
  __shared__ float red[8];
  if (lane == 0) { red[wave] = s; red[4 + wave] = s2; }
  __syncthreads();
  s = red[0] + red[1] + red[2] + red[3];
  s2 = red[4] + red[5] + red[6] + red[7];
  const float mu = s * (1.f / DIM);
  const float var = s2 * (1.f / DIM) - mu * mu;
  const float rstd = rsqrtf(var + 1e-5f);
  float4 wv = *(const float4*)&w[t * 4];
  float4 bv = *(const float4*)&b[t * 4];
  ushort4 o;
  o.x = f2bf((v.x - mu) * rstd * wv.x + bv.x);
  o.y = f2bf((v.y - mu) * rstd * wv.y + bv.y);
  o.z = f2bf((v.z - mu) * rstd * wv.z + bv.z);
  o.w = f2bf((v.w - mu) * rstd * wv.w + bv.w);
  *(ushort4*)&out[(size_t)row * DIM + t * 4] = o;
}

// ---------------- GEMM: C[M][N] = A[M][K](bf16) x Bt[N][K](bf16) + bias ----------------
// m97 structure: 128x128 tile, BK=32, 4 waves, global_load_lds width 16.
// MODE 0: QKV scatter (Q scaled 0.125)  1: +res -> fp32  2: GELU -> bf16  3: +res -> fp32
template <int MODE>
__global__ __launch_bounds__(256) void gemm_bt(
    const unsigned short* __restrict__ A,
    const unsigned short* __restrict__ Bt,
    const float* __restrict__ bias,
    const float* resf, float* outf, unsigned short* outb,
    unsigned short* Qo, unsigned short* Ko, unsigned short* Vto,
    int M, int N, int K)
{
  __shared__ __align__(16) unsigned short sA[128 * 32];
  __shared__ __align__(16) unsigned short sB[128 * 32];
  const int tid = threadIdx.x;
  const int wave = tid >> 6, lane = tid & 63;

  // bijective XCD swizzle (all grids have nwg % 8 == 0)
  const int nbx = gridDim.x;
  const int nwg = nbx * gridDim.y;
  const int bid = blockIdx.y * nbx + blockIdx.x;
  const int cpx = nwg >> 3;
  const int swz = (bid & 7) * cpx + (bid >> 3);
  const int n0 = (swz % nbx) * 128;
  const int m0 = (swz / nbx) * 128;

  const int srow = wave * 16 + (lane >> 2);
  const int scol = (lane & 3) * 8;
  const unsigned short* gA = A + (size_t)(m0 + srow) * K + scol;
  const unsigned short* gB = Bt + (size_t)(n0 + srow) * K + scol;
  unsigned short* lA0 = sA + wave * 512;
  unsigned short* lA1 = sA + 2048 + wave * 512;
  unsigned short* lB0 = sB + wave * 512;
  unsigned short* lB1 = sB + 2048 + wave * 512;
  const size_t rstep = (size_t)64 * K;

  const int wr = wave >> 1, wc = wave & 1;
  const int fl = lane & 15, fh = lane >> 4;
  f32x4 acc[4][4] = {};

  for (int k0 = 0; k0 < K; k0 += 32) {
    gload_lds16(gA + k0, lA0);
    gload_lds16(gA + rstep + k0, lA1);
    gload_lds16(gB + k0, lB0);
    gload_lds16(gB + rstep + k0, lB1);
    __syncthreads();
    bf16x8 af[4], bfr[4];
#pragma unroll
    for (int f = 0; f < 4; ++f)
      af[f] = *(const bf16x8*)&sA[(wr * 64 + f * 16 + fl) * 32 + fh * 8];
#pragma unroll
    for (int f = 0; f < 4; ++f)
      bfr[f] = *(const bf16x8*)&sB[(wc * 64 + f * 16 + fl) * 32 + fh * 8];
#pragma unroll
    for (int i = 0; i < 4; ++i)
#pragma unroll
      for (int j = 0; j < 4; ++j)
        acc[i][j] = __builtin_amdgcn_mfma_f32_16x16x32_bf16(af[i], bfr[j], acc[i][j], 0, 0, 0);
    __syncthreads();
  }

#pragma unroll
  for (int i = 0; i < 4; ++i) {
    const int rowb = m0 + wr * 64 + i * 16 + fh * 4;
#pragma unroll
    for (int j = 0; j < 4; ++j) {
      const int col = n0 + wc * 64 + j * 16 + fl;
      const float bv = bias[col];
#pragma unroll
      for (int r = 0; r < 4; ++r) {
        const int row = rowb + r;
        float v = acc[i][j][r] + bv;
        if constexpr (MODE == 0) {
          const int which = col >> 10;
          const int h = (col >> 6) & 15;
          const int d = col & 63;
          const int b = row >> 11, s = row & 2047;
          const size_t bh = (size_t)(b * 16 + h);
          if (which == 0)      Qo[(bh * SEQ + s) * HD + d] = f2bf(v * 0.125f);
          else if (which == 1) Ko[(bh * SEQ + s) * HD + d] = f2bf(v);
          else                 Vto[(bh * HD + d) * SEQ + s] = f2bf(v);
        } else if constexpr (MODE == 2) {
          const float g = 0.5f * v * (1.0f + erff(v * 0.70710678118f));
          outb[(size_t)row * N + col] = f2bf(g);
        } else {
          outf[(size_t)row * N + col] = resf[(size_t)row * N + col] + v;
        }
      }
    }
  }
}

// ---------------- causal flash attention (v2) ----------------
// grid (32 qtiles heavy-first, 64 bh); 4 waves; each wave owns 16 q-rows.
// K/V tiles (64 rows) staged in LDS via global_load_lds, double-buffered,
// shared by all 4 waves. XOR-swizzled layout (byte ^= (row&7)<<4) applied
// via pre-swizzled GLOBAL source (linear LDS dest) so ds_read_b128 B-frags
// are conflict-free.
__global__ __launch_bounds__(256) void attn_kernel(
    const unsigned short* __restrict__ Q,
    const unsigned short* __restrict__ Kt,
    const unsigned short* __restrict__ Vt,
    unsigned short* __restrict__ Ao)
{
  __shared__ __align__(16) char sK[2][8192];
  __shared__ __align__(16) char sV[2][8192];
  __shared__ __align__(16) char sP[4][2048];

  const int qt = 31 - blockIdx.x;            // heavy blocks dispatch first
  const int bh = blockIdx.y;
  const int wave = threadIdx.x >> 6, lane = threadIdx.x & 63;
  const int fl = lane & 15, fh = lane >> 4;
  const int q0 = qt * 64;
  const int qw = q0 + wave * 16;
  const char* Kb = (const char*)(Kt + (size_t)bh * SEQ * HD);
  const char* Vb = (const char*)(Vt + (size_t)bh * HD * SEQ);
  const unsigned short* Qb = Q + (size_t)bh * SEQ * HD;
  char* pbase = sP[wave];

  // staging geometry: chunk = 1KB (one wave-issue), 8 chunks per 8KB tile.
  const int sg_chunk0 = wave;                 // chunks wave, wave+4
  const int sg_row_in = lane >> 3;            // 0..7 within chunk (row&7)
  const int sg_colb = ((lane & 7) * 16) ^ (sg_row_in << 4); // pre-swizzled src col

  // Q fragment held in registers for the whole kernel (A-operand, 16 rows)
  bf16x8 aq[2];
#pragma unroll
  for (int kk = 0; kk < 2; ++kk)
    aq[kk] = *(const bf16x8*)&Qb[(size_t)(qw + fl) * HD + kk * 32 + fh * 8];

  f32x4 accO[4] = {};
  float mr[4], lr[4];
#pragma unroll
  for (int r = 0; r < 4; ++r) { mr[r] = -1e30f; lr[r] = 0.f; }

  const int nkt = qt + 1;

  // prologue: stage tile 0 into buf 0
#pragma unroll
  for (int i = 0; i < 2; ++i) {
    const int chunk = i * 4 + sg_chunk0;
    const int row = chunk * 8 + sg_row_in;
    gload_lds16(Kb + (size_t)row * 128 + sg_colb, sK[0] + chunk * 1024);
    gload_lds16(Vb + (size_t)row * (SEQ * 2) + sg_colb, sV[0] + chunk * 1024);
  }
  __syncthreads();

  for (int t = 0; t < nkt; ++t) {
    const int kbase = t * 64;
    const int cur = t & 1;
    if (t + 1 < nkt) { // prefetch next tile into other buffer
      const int kb2 = kbase + 64;
#pragma unroll
      for (int i = 0; i < 2; ++i) {
        const int chunk = i * 4 + sg_chunk0;
        const int row = chunk * 8 + sg_row_in;
        gload_lds16(Kb + (size_t)(kb2 + row) * 128 + sg_colb, sK[cur ^ 1] + chunk * 1024);
        gload_lds16(Vb + (size_t)row * (SEQ * 2) + kb2 * 2 + sg_colb, sV[cur ^ 1] + chunk * 1024);
      }
    }

    // ---- QK^T ----
    f32x4 accS[4] = {};
    __builtin_amdgcn_s_setprio(1);
#pragma unroll
    for (int kk = 0; kk < 2; ++kk) {
      const int cb = (kk * 64 + fh * 16) ^ ((fl & 7) << 4);
#pragma unroll
      for (int fc = 0; fc < 4; ++fc) {
        const bf16x8 bk = *(const bf16x8*)(sK[cur] + (fc * 16 + fl) * 128 + cb);
        accS[fc] = __builtin_amdgcn_mfma_f32_16x16x32_bf16(aq[kk], bk, accS[fc], 0, 0, 0);
      }
    }
    __builtin_amdgcn_s_setprio(0);

    if (t == nkt - 1) { // causal mask (only the diagonal tile needs it)
#pragma unroll
      for (int fc = 0; fc < 4; ++fc)
#pragma unroll
        for (int r = 0; r < 4; ++r) {
          const int colk = kbase + fc * 16 + fl;
          const int rowq = qw + fh * 4 + r;
          if (colk > rowq) accS[fc][r] = -1e30f;
        }
    }

    // ---- online softmax (rows: fh*4+r, cols across fl) ----
#pragma unroll
    for (int r = 0; r < 4; ++r) {
      float mx = fmaxf(fmaxf(accS[0][r], accS[1][r]), fmaxf(accS[2][r], accS[3][r]));
      mx = fmaxf(mx, __shfl_xor(mx, 1));
      mx = fmaxf(mx, __shfl_xor(mx, 2));
      mx = fmaxf(mx, __shfl_xor(mx, 4));
      mx = fmaxf(mx, __shfl_xor(mx, 8));
      const float mnew = fmaxf(mr[r], mx);
      const float alpha = __expf(mr[r] - mnew);
      mr[r] = mnew;
      float rs = 0.f;
#pragma unroll
      for (int fc = 0; fc < 4; ++fc) {
        const float p = __expf(accS[fc][r] - mnew);
        accS[fc][r] = p;
        rs += p;
      }
      rs += __shfl_xor(rs, 1);
      rs += __shfl_xor(rs, 2);
      rs += __shfl_xor(rs, 4);
      rs += __shfl_xor(rs, 8);
      lr[r] = lr[r] * alpha + rs;
#pragma unroll
      for (int dc = 0; dc < 4; ++dc)
        accO[dc][r] *= alpha;
    }

    // ---- P -> LDS (bf16, per-wave region, same XOR swizzle) ----
#pragma unroll
    for (int fc = 0; fc < 4; ++fc)
#pragma unroll
      for (int r = 0; r < 4; ++r) {
        const int prow = fh * 4 + r;
        const int cb = (fc * 16 + fl) * 2;
        *(unsigned short*)(pbase + prow * 128 + (cb ^ ((prow & 7) << 4))) = f2bf(accS[fc][r]);
      }

    // ---- PV ----
    __builtin_amdgcn_s_setprio(1);
#pragma unroll
    for (int kk = 0; kk < 2; ++kk) {
      const int cb = (kk * 64 + fh * 16) ^ ((fl & 7) << 4);
      const bf16x8 ap = *(const bf16x8*)(pbase + fl * 128 + cb);
#pragma unroll
      for (int dc = 0; dc < 4; ++dc) {
        const bf16x8 bv = *(const bf16x8*)(sV[cur] + (dc * 16 + fl) * 128 + cb);
        accO[dc] = __builtin_amdgcn_mfma_f32_16x16x32_bf16(ap, bv, accO[dc], 0, 0, 0);
      }
    }
    __builtin_amdgcn_s_setprio(0);

    __syncthreads(); // drains prefetch (vmcnt 0) + protects buffer reuse
  }

  const int b = bh >> 4, h = bh & 15;
#pragma unroll
  for (int dc = 0; dc < 4; ++dc)
#pragma unroll
    for (int r = 0; r < 4; ++r) {
      const int row = qw + fh * 4 + r;
      const int col = h * HD + dc * 16 + fl;
      const float v = accO[dc][r] / lr[r];
      Ao[((size_t)b * SEQ + row) * DIM + col] = f2bf(v);
    }
}

// ---------------- launcher ----------------
extern "C" void kernel_launch(void* const* d_in, const int* in_sizes, int n_in,
                              void* d_out, int out_size, void* d_ws, size_t ws_size,
                              hipStream_t stream)
{
  const float* x      = (const float*)d_in[0];
  const float* ln1_w  = (const float*)d_in[1];
  const float* ln1_b  = (const float*)d_in[2];
  const float* qkv_w  = (const float*)d_in[3];
  const float* qkv_b  = (const float*)d_in[4];
  const float* proj_w = (const float*)d_in[5];
  const float* proj_b = (const float*)d_in[6];
  const float* ln2_w  = (const float*)d_in[7];
  const float* ln2_b  = (const float*)d_in[8];
  const float* fc1_w  = (const float*)d_in[9];
  const float* fc1_b  = (const float*)d_in[10];
  const float* fc2_w  = (const float*)d_in[11];
  const float* fc2_b  = (const float*)d_in[12];
  float* out = (float*)d_out;
  unsigned short* ws = (unsigned short*)d_ws;

  // ws layout (bf16 element offsets); total = 125,829,120 bytes
  unsigned short* wqkv = ws;                 // [3072][1024]
  unsigned short* wproj = ws + 3145728;      // [1024][1024]
  unsigned short* wfc1 = ws + 4194304;       // [4096][1024]
  unsigned short* wfc2 = ws + 8388608;       // [1024][4096]
  unsigned short* xn1  = ws + 12582912;      // [8192][1024]
  unsigned short* Qb   = ws + 20971520;      // [B,H,S,D]
  unsigned short* Kb   = ws + 29360128;      // [B,H,S,D]
  unsigned short* Vtb  = ws + 37748736;      // [B,H,D,S]
  unsigned short* aout = xn1;                // reuse (xn1 dead after QKV gemm)
  unsigned short* hn   = Qb;                 // reuse (Q dead after attention)
  unsigned short* hbuf = Kb;                 // [8192][4096] overlaps K/Vt (dead)

  transpose_w_kernel<<<dim3(48, 16), 256, 0, stream>>>(qkv_w, wqkv, 1024, 3072);
  transpose_w_kernel<<<dim3(16, 16), 256, 0, stream>>>(proj_w, wproj, 1024, 1024);
  transpose_w_kernel<<<dim3(64, 16), 256, 0, stream>>>(fc1_w, wfc1, 1024, 4096);
  transpose_w_kernel<<<dim3(16, 64), 256, 0, stream>>>(fc2_w, wfc2, 4096, 1024);

  ln_kernel<<<ROWS, 256, 0, stream>>>(x, ln1_w, ln1_b, xn1);

  gemm_bt<0><<<dim3(24, 64), 256, 0, stream>>>(xn1, wqkv, qkv_b,
      nullptr, nullptr, nullptr, Qb, Kb, Vtb, ROWS, 3072, 1024);

  attn_kernel<<<dim3(32, 64), 256, 0, stream>>>(Qb, Kb, Vtb, aout);

  gemm_bt<1><<<dim3(8, 64), 256, 0, stream>>>(aout, wproj, proj_b,
      x, out, nullptr, nullptr, nullptr, nullptr, ROWS, 1024, 1024);

  ln_kernel<<<ROWS, 256, 0, stream>>>(out, ln2_w, ln2_b, hn);

  gemm_bt<2><<<dim3(32, 64), 256, 0, stream>>>(hn, wfc1, fc1_b,
      nullptr, nullptr, hbuf, nullptr, nullptr, nullptr, ROWS, 4096, 1024);

  gemm_bt<3><<<dim3(8, 64), 256, 0, stream>>>(hbuf, wfc2, fc2_b,
      out, out, nullptr, nullptr, nullptr, nullptr, ROWS, 1024, 4096);
}